// Round 6
// baseline (1158.958 us; speedup 1.0000x reference)
//
#include <hip/hip_runtime.h>
#include <math.h>

#define NB_ROWS 8192
#define DDIM 1024
#define PSZ ((size_t)NB_ROWS * DDIM)

typedef _Float16 f16x8 __attribute__((ext_vector_type(8)));
typedef _Float16 f16x4 __attribute__((ext_vector_type(4)));
typedef float f32x4 __attribute__((ext_vector_type(4)));

#define LO_SCALE 1024.0f
#define LO_INV (1.0f / 1024.0f)

__device__ __forceinline__ void gload_lds16(const void* g, void* l) {
  __builtin_amdgcn_global_load_lds((const __attribute__((address_space(1))) void*)g,
                                   (__attribute__((address_space(3))) void*)l, 16, 0, 0);
}

// LDS byte offset of a __shared__ pointer (AS3 pointers are 32-bit offsets)
__device__ __forceinline__ unsigned lds_off(const void* p) {
  return (unsigned)(size_t)(const __attribute__((address_space(3))) void*)p;
}

// opaque ds_read_b128: invisible to compiler alias analysis, so no conservative
// vmcnt(0) is inserted between in-flight global_load_lds and this read.
// MUST be followed by s_waitcnt lgkmcnt(0) + sched_barrier(0) before use (rule #18).
__device__ __forceinline__ f16x8 ds_read128(unsigned addr) {
  f32x4 d;
  asm volatile("ds_read_b128 %0, %1" : "=v"(d) : "v"(addr));
  union { f32x4 f; f16x8 h; } u;
  u.f = d;
  return u.h;
}

__device__ __forceinline__ bool pair_better(float s, int j, float v, int i) {
  return (s > v) || (s == v && j < i);
}

__device__ __forceinline__ void upd3(float s, int jj, float& v0, int& i0,
                                     float& v1, int& i1, float& v2, int& i2) {
  if (pair_better(s, jj, v0, i0)) { v2 = v1; i2 = i1; v1 = v0; i1 = i0; v0 = s; i0 = jj; }
  else if (pair_better(s, jj, v1, i1)) { v2 = v1; i2 = i1; v1 = s; i1 = jj; }
  else if (pair_better(s, jj, v2, i2)) { v2 = s; i2 = jj; }
}

// merge sorted triple (v) with sorted triple (b) -> sorted top-3 in (v)
__device__ __forceinline__ void merge3(float& v0, int& i0, float& v1, int& i1,
                                       float& v2, int& i2, float b0, int jb0,
                                       float b1, int jb1, float b2, int jb2) {
  float r0, r1, r2; int q0, q1, q2;
  if (pair_better(v0, i0, b0, jb0)) {
    r0 = v0; q0 = i0;
    if (pair_better(v1, i1, b0, jb0)) {
      r1 = v1; q1 = i1;
      if (pair_better(v2, i2, b0, jb0)) { r2 = v2; q2 = i2; } else { r2 = b0; q2 = jb0; }
    } else {
      r1 = b0; q1 = jb0;
      if (pair_better(v1, i1, b1, jb1)) { r2 = v1; q2 = i1; } else { r2 = b1; q2 = jb1; }
    }
  } else {
    r0 = b0; q0 = jb0;
    if (pair_better(v0, i0, b1, jb1)) {
      r1 = v0; q1 = i0;
      if (pair_better(v1, i1, b1, jb1)) { r2 = v1; q2 = i1; } else { r2 = b1; q2 = jb1; }
    } else {
      r1 = b1; q1 = jb1;
      if (pair_better(v0, i0, b2, jb2)) { r2 = v0; q2 = i0; } else { r2 = b2; q2 = jb2; }
    }
  }
  v0 = r0; i0 = q0; v1 = r1; i1 = q1; v2 = r2; i2 = q2;
}

// ---------------- scan: bank2batch + query list per modality ----------------
__global__ void scan_kernel(const int* __restrict__ miss, int* __restrict__ meta,
                            int* __restrict__ b2b, int* __restrict__ qrw) {
  const int m = blockIdx.x, t = threadIdx.x, tmod = m + 1;
  __shared__ int cnt[256];
  const int base = t * 32;
  int c = 0;
  for (int i = 0; i < 32; ++i) c += (miss[base + i] != tmod) ? 1 : 0;
  cnt[t] = c; __syncthreads();
  for (int s = 1; s < 256; s <<= 1) {
    int v = (t >= s) ? cnt[t - s] : 0;
    __syncthreads();
    cnt[t] += v;
    __syncthreads();
  }
  const int Nb = cnt[255];
  int pos = cnt[t] - c;
  for (int i = 0; i < 32; ++i) {
    int r = base + i;
    if (miss[r] != tmod) b2b[m * NB_ROWS + (pos++)] = r;
  }
  __syncthreads();
  int q = 0;
  for (int i = 0; i < 32; ++i) {
    int r = base + i;
    q += (miss[r] == tmod && r < Nb) ? 1 : 0;
  }
  cnt[t] = q; __syncthreads();
  for (int s = 1; s < 256; s <<= 1) {
    int v = (t >= s) ? cnt[t - s] : 0;
    __syncthreads();
    cnt[t] += v;
    __syncthreads();
  }
  int nQ = cnt[255];
  if (nQ > 4096) nQ = 4096;
  int qpos = cnt[t] - q;
  for (int i = 0; i < 32; ++i) {
    int r = base + i;
    if (miss[r] == tmod && r < Nb && qpos < 4096) qrw[m * 4096 + (qpos++)] = r;
  }
  for (int i = nQ + t; i < 4096; i += 256) qrw[m * 4096 + i] = 0;  // pad tail
  if (t == 0) { meta[2 * m] = Nb; meta[2 * m + 1] = nQ; }
}

// ------------- transpose + fp16 split: W[K][N] -> Th/Tl[N][K] ---------------
__global__ void tsplit(const float* __restrict__ W, _Float16* __restrict__ Th,
                       _Float16* __restrict__ Tl, int K, int N) {
  __shared__ float tile[32][33];
  const int k0 = blockIdx.x * 32, n0 = blockIdx.y * 32;
  const int tx = threadIdx.x, ty = threadIdx.y;
  for (int i = ty; i < 32; i += 8)
    tile[i][tx] = W[(size_t)(k0 + i) * N + n0 + tx];
  __syncthreads();
  for (int i = ty; i < 32; i += 8) {
    float v = tile[tx][i];
    _Float16 h = (_Float16)v;
    Th[(size_t)(n0 + i) * K + k0 + tx] = h;
    if (Tl) Tl[(size_t)(n0 + i) * K + k0 + tx] = (_Float16)((v - (float)h) * LO_SCALE);
  }
}

__device__ __forceinline__ f16x8 cvt_hi8(float4 a, float4 b) {
  f16x8 r;
  r[0] = (_Float16)a.x; r[1] = (_Float16)a.y; r[2] = (_Float16)a.z; r[3] = (_Float16)a.w;
  r[4] = (_Float16)b.x; r[5] = (_Float16)b.y; r[6] = (_Float16)b.z; r[7] = (_Float16)b.w;
  return r;
}
__device__ __forceinline__ f16x8 cvt_lo8(float4 a, float4 b, f16x8 h) {
  f16x8 r;
  r[0] = (_Float16)((a.x - (float)h[0]) * LO_SCALE);
  r[1] = (_Float16)((a.y - (float)h[1]) * LO_SCALE);
  r[2] = (_Float16)((a.z - (float)h[2]) * LO_SCALE);
  r[3] = (_Float16)((a.w - (float)h[3]) * LO_SCALE);
  r[4] = (_Float16)((b.x - (float)h[4]) * LO_SCALE);
  r[5] = (_Float16)((b.y - (float)h[5]) * LO_SCALE);
  r[6] = (_Float16)((b.z - (float)h[6]) * LO_SCALE);
  r[7] = (_Float16)((b.w - (float)h[7]) * LO_SCALE);
  return r;
}

// ------------- row-major fp16 split: X fp32 -> Ah/Al (same layout) ----------
__global__ void xsplit(const float* __restrict__ X, _Float16* __restrict__ Ah,
                       _Float16* __restrict__ Al) {
  const size_t idx = ((size_t)blockIdx.x * 256 + threadIdx.x) * 8;
  float4 f0 = *(const float4*)(X + idx);
  float4 f1 = *(const float4*)(X + idx + 4);
  f16x8 hi = cvt_hi8(f0, f1);
  f16x8 lo = cvt_lo8(f0, f1, hi);
  *(f16x8*)(Ah + idx) = hi;
  *(f16x8*)(Al + idx) = lo;
}

// ---- MFMA split GEMM (round-2 proven form, compiler-scheduled ds_reads):
//      proj = A(hi/lo)[8192,2048] @ Bt(hi/lo)[1024,2048]^T + bias
__launch_bounds__(256, 2)
__global__ void gemm_proj_mfma(const _Float16* __restrict__ Ah, const _Float16* __restrict__ Al,
                               const _Float16* __restrict__ Bh, const _Float16* __restrict__ Bl,
                               const float* __restrict__ bias,
                               _Float16* __restrict__ Ph, _Float16* __restrict__ Pl) {
  const int K = 2048;
  __shared__ __align__(16) _Float16 Abuf[128 * 64];
  __shared__ __align__(16) _Float16 Bbuf[128 * 64];
  const int t = threadIdx.x;
  const int w = t >> 6, ln = t & 63;
  const int n0 = blockIdx.x * 128, m0 = blockIdx.y * 128;
  const int moff = (w & 1) * 64, noff = (w >> 1) * 64;
  const int lq = ln >> 4, lr = ln & 15;

  const _Float16* as[4]; const _Float16* bs[4];
  _Float16* ad[4]; _Float16* bd[4];
#pragma unroll
  for (int p = 0; p < 4; ++p) {
    int r = p * 32 + w * 8 + (ln >> 3);
    int l = (ln & 7) ^ (r & 7);
    as[p] = (l < 4) ? (Ah + (size_t)(m0 + r) * K + l * 8)
                    : (Al + (size_t)(m0 + r) * K + (l - 4) * 8);
    bs[p] = (l < 4) ? (Bh + (size_t)(n0 + r) * K + l * 8)
                    : (Bl + (size_t)(n0 + r) * K + (l - 4) * 8);
    ad[p] = &Abuf[(p * 32 + w * 8) * 64];
    bd[p] = &Bbuf[(p * 32 + w * 8) * 64];
  }

  f32x4 acc[4][4] = {};
  f32x4 acc2[4][4] = {};

  for (int k0 = 0; k0 < K; k0 += 32) {
#pragma unroll
    for (int p = 0; p < 4; ++p) {
      gload_lds16(as[p] + k0, ad[p]);
      gload_lds16(bs[p] + k0, bd[p]);
    }
    __syncthreads();
    f16x8 ahi[4], alo[4];
#pragma unroll
    for (int mt = 0; mt < 4; ++mt) {
      int r = moff + mt * 16 + lr;
      ahi[mt] = *(f16x8*)&Abuf[r * 64 + ((lq) ^ (r & 7)) * 8];
      alo[mt] = *(f16x8*)&Abuf[r * 64 + ((lq + 4) ^ (r & 7)) * 8];
    }
#pragma unroll
    for (int nt = 0; nt < 4; ++nt) {
      int r = noff + nt * 16 + lr;
      f16x8 bhi = *(f16x8*)&Bbuf[r * 64 + ((lq) ^ (r & 7)) * 8];
      f16x8 blo = *(f16x8*)&Bbuf[r * 64 + ((lq + 4) ^ (r & 7)) * 8];
#pragma unroll
      for (int mt = 0; mt < 4; ++mt) {
        acc[mt][nt]  = __builtin_amdgcn_mfma_f32_16x16x32_f16(ahi[mt], bhi, acc[mt][nt], 0, 0, 0);
        acc2[mt][nt] = __builtin_amdgcn_mfma_f32_16x16x32_f16(ahi[mt], blo, acc2[mt][nt], 0, 0, 0);
        acc2[mt][nt] = __builtin_amdgcn_mfma_f32_16x16x32_f16(alo[mt], bhi, acc2[mt][nt], 0, 0, 0);
      }
    }
    __syncthreads();
  }
#pragma unroll
  for (int nt = 0; nt < 4; ++nt) {
    int col = n0 + noff + nt * 16 + lr;
    float bv = bias[col];
#pragma unroll
    for (int mt = 0; mt < 4; ++mt) {
      int row = m0 + moff + mt * 16 + lq * 4;
#pragma unroll
      for (int r = 0; r < 4; ++r) {
        float v = acc[mt][nt][r] + acc2[mt][nt][r] * LO_INV + bv;
        _Float16 h = (_Float16)v;
        Ph[(size_t)(row + r) * DDIM + col] = h;
        Pl[(size_t)(row + r) * DDIM + col] = (_Float16)((v - (float)h) * LO_SCALE);
      }
    }
  }
}

// top-3 of this lane-group's 64 columns for one physical row (16 lanes x 4 vals)
__device__ __forceinline__ void sel3_row(const float* bv, const int* bi,
                                         float& v0, int& i0, float& v1, int& i1,
                                         float& v2, int& i2) {
  float lm; int li;
  // pass 0
  lm = -INFINITY; li = 0x7fffffff;
#pragma unroll
  for (int nt = 0; nt < 4; ++nt)
    if (pair_better(bv[nt], bi[nt], lm, li)) { lm = bv[nt]; li = bi[nt]; }
#pragma unroll
  for (int mk = 1; mk <= 8; mk <<= 1) {
    float ov = __shfl_xor(lm, mk, 64); int oi = __shfl_xor(li, mk, 64);
    if (pair_better(ov, oi, lm, li)) { lm = ov; li = oi; }
  }
  v0 = lm; i0 = li;
  // pass 1 (exclude i0 by index; indices are unique)
  lm = -INFINITY; li = 0x7fffffff;
#pragma unroll
  for (int nt = 0; nt < 4; ++nt)
    if (bi[nt] != i0 && pair_better(bv[nt], bi[nt], lm, li)) { lm = bv[nt]; li = bi[nt]; }
#pragma unroll
  for (int mk = 1; mk <= 8; mk <<= 1) {
    float ov = __shfl_xor(lm, mk, 64); int oi = __shfl_xor(li, mk, 64);
    if (pair_better(ov, oi, lm, li)) { lm = ov; li = oi; }
  }
  v1 = lm; i1 = li;
  // pass 2 (exclude i0, i1)
  lm = -INFINITY; li = 0x7fffffff;
#pragma unroll
  for (int nt = 0; nt < 4; ++nt)
    if (bi[nt] != i0 && bi[nt] != i1 && pair_better(bv[nt], bi[nt], lm, li)) { lm = bv[nt]; li = bi[nt]; }
#pragma unroll
  for (int mk = 1; mk <= 8; mk <<= 1) {
    float ov = __shfl_xor(lm, mk, 64); int oi = __shfl_xor(li, mk, 64);
    if (pair_better(ov, oi, lm, li)) { lm = ov; li = oi; }
  }
  v2 = lm; i2 = li;
}

// ---- compact query gather: Q[i] = bank[qrw[i]] (contiguous A for sim) ------
__global__ void qgather(const _Float16* __restrict__ bnh, const _Float16* __restrict__ bnl,
                        const int* __restrict__ qrw_m, const int* __restrict__ meta, int mmod,
                        _Float16* __restrict__ Qh, _Float16* __restrict__ Ql) {
  const int q = blockIdx.x, t = threadIdx.x;
  const int nQ = meta[2 * mmod + 1];
  const size_t o = (size_t)q * DDIM + t * 4;
  if (q >= nQ) {
    *(f16x4*)&Qh[o] = (f16x4)0;
    *(f16x4*)&Ql[o] = (f16x4)0;
    return;
  }
  const size_t s = (size_t)qrw_m[q] * DDIM + t * 4;
  *(f16x4*)&Qh[o] = *(const f16x4*)&bnh[s];
  *(f16x4*)&Ql[o] = *(const f16x4*)&bnl[s];
}

// ---- MFMA split sim + fused masked top-3, dbuf + asm-ds_read overlap -------
// (round-5 proven form: 222 -> 134 us). Identity block mapping keeps each
// XCD's B-panels L2-resident.
__launch_bounds__(256, 2)
__global__ void gemm_sim_topk(const _Float16* __restrict__ bh, const _Float16* __restrict__ bl,
                              const _Float16* __restrict__ Qh, const _Float16* __restrict__ Ql,
                              const int* __restrict__ meta, const int* __restrict__ miss,
                              int mmod, float* __restrict__ cvals, int* __restrict__ cidx) {
  const int Nb = meta[2 * mmod], nQ = meta[2 * mmod + 1];
  const int n0 = blockIdx.x * 128, m0 = blockIdx.y * 128;
  if (m0 >= nQ || n0 >= Nb) return;
  __shared__ __align__(16) _Float16 Abuf[2][128 * 64];
  __shared__ __align__(16) _Float16 Bbuf[2][128 * 64];
  __shared__ float csv[128][2][3];
  __shared__ int   csi[128][2][3];
  const int t = threadIdx.x;
  const int w = t >> 6, ln = t & 63;
  const int moff = (w & 1) * 64, noff = (w >> 1) * 64;
  const int lq = ln >> 4, lr = ln & 15;

  const _Float16* as[4]; const _Float16* bs[4]; int doff[4];
#pragma unroll
  for (int p = 0; p < 4; ++p) {
    int r = p * 32 + w * 8 + (ln >> 3);
    int l = (ln & 7) ^ (r & 7);
    as[p] = (l < 4) ? (Qh + (size_t)(m0 + r) * DDIM + l * 8)
                    : (Ql + (size_t)(m0 + r) * DDIM + (l - 4) * 8);
    bs[p] = (l < 4) ? (bh + (size_t)(n0 + r) * DDIM + l * 8)
                    : (bl + (size_t)(n0 + r) * DDIM + (l - 4) * 8);
    doff[p] = (p * 32 + w * 8) * 64;
  }
  unsigned aoh[4], aol[4], boh[4], bol[4];
#pragma unroll
  for (int mt = 0; mt < 4; ++mt) {
    int r = moff + mt * 16 + lr;
    aoh[mt] = (unsigned)(r * 64 + ((lq) ^ (r & 7)) * 8) * 2u;
    aol[mt] = (unsigned)(r * 64 + ((lq + 4) ^ (r & 7)) * 8) * 2u;
    int rn = noff + mt * 16 + lr;
    boh[mt] = (unsigned)(rn * 64 + ((lq) ^ (rn & 7)) * 8) * 2u;
    bol[mt] = (unsigned)(rn * 64 + ((lq + 4) ^ (rn & 7)) * 8) * 2u;
  }
  const unsigned abase = lds_off(&Abuf[0][0]);
  const unsigned bbase = lds_off(&Bbuf[0][0]);

  f32x4 acc[4][4] = {};
  f32x4 acc2[4][4] = {};

  // prologue: stage k=0 into buffer 0
#pragma unroll
  for (int p = 0; p < 4; ++p) {
    gload_lds16(as[p], &Abuf[0][doff[p]]);
    gload_lds16(bs[p], &Bbuf[0][doff[p]]);
  }
  __syncthreads();

  unsigned cursel = 0;
  for (int k0 = 0; k0 < DDIM; k0 += 32) {
    if (k0 + 32 < DDIM) {
      const unsigned ns = cursel ^ 1u;
#pragma unroll
      for (int p = 0; p < 4; ++p) {
        gload_lds16(as[p] + k0 + 32, &Abuf[ns][doff[p]]);
        gload_lds16(bs[p] + k0 + 32, &Bbuf[ns][doff[p]]);
      }
    }
    const unsigned ab = abase + cursel * 16384u;
    const unsigned bb = bbase + cursel * 16384u;
    f16x8 ahi[4], alo[4], bhi[4], blo[4];
#pragma unroll
    for (int mt = 0; mt < 4; ++mt) { ahi[mt] = ds_read128(ab + aoh[mt]); alo[mt] = ds_read128(ab + aol[mt]); }
#pragma unroll
    for (int nt = 0; nt < 4; ++nt) { bhi[nt] = ds_read128(bb + boh[nt]); blo[nt] = ds_read128(bb + bol[nt]); }
    asm volatile("s_waitcnt lgkmcnt(0)" ::: "memory");
    __builtin_amdgcn_sched_barrier(0);
#pragma unroll
    for (int nt = 0; nt < 4; ++nt)
#pragma unroll
      for (int mt = 0; mt < 4; ++mt) {
        acc[mt][nt]  = __builtin_amdgcn_mfma_f32_16x16x32_f16(ahi[mt], bhi[nt], acc[mt][nt], 0, 0, 0);
        acc2[mt][nt] = __builtin_amdgcn_mfma_f32_16x16x32_f16(ahi[mt], blo[nt], acc2[mt][nt], 0, 0, 0);
        acc2[mt][nt] = __builtin_amdgcn_mfma_f32_16x16x32_f16(alo[mt], bhi[nt], acc2[mt][nt], 0, 0, 0);
      }
    __syncthreads();
    cursel ^= 1u;
  }

  // fused epilogue: per-row masked top-3 from accumulators (no S write)
  bool okc[4]; int colg[4];
#pragma unroll
  for (int nt = 0; nt < 4; ++nt) {
    int col = n0 + noff + nt * 16 + lr;
    colg[nt] = col;
    okc[nt] = (col < Nb) && (miss[col] != mmod + 1);  // col_valid, batch-indexed (source bug kept)
  }
  const int nh = w >> 1;
#pragma unroll
  for (int mt = 0; mt < 4; ++mt) {
#pragma unroll
    for (int r = 0; r < 4; ++r) {
      float bv[4];
#pragma unroll
      for (int nt = 0; nt < 4; ++nt)
        bv[nt] = okc[nt] ? (acc[mt][nt][r] + acc2[mt][nt][r] * LO_INV) : -INFINITY;
      float v0, v1, v2; int i0, i1, i2;
      sel3_row(bv, colg, v0, i0, v1, i1, v2, i2);
      if (lr == 0) {
        int row = moff + mt * 16 + lq * 4 + r;
        csv[row][nh][0] = v0; csi[row][nh][0] = i0;
        csv[row][nh][1] = v1; csi[row][nh][1] = i1;
        csv[row][nh][2] = v2; csi[row][nh][2] = i2;
      }
    }
  }
  __syncthreads();
  if (t < 128) {
    float v0 = -INFINITY, v1 = -INFINITY, v2 = -INFINITY;
    int i0 = 0x7fffffff, i1 = 0x7fffffff, i2 = 0x7fffffff;
#pragma unroll
    for (int h = 0; h < 2; ++h)
#pragma unroll
      for (int s = 0; s < 3; ++s)
        upd3(csv[t][h][s], csi[t][h][s], v0, i0, v1, i1, v2, i2);
    const size_t o = ((size_t)(m0 + t) * 64 + (size_t)(n0 >> 7)) * 3;
    cvals[o + 0] = v0; cidx[o + 0] = i0;
    cvals[o + 1] = v1; cidx[o + 1] = i1;
    cvals[o + 2] = v2; cidx[o + 2] = i2;
  }
}

// ---- merge per-block candidates -> global top-3 -> softmax-weighted fill ---
__launch_bounds__(256)
__global__ void knn_fill(const float* __restrict__ cvals, const int* __restrict__ cidx,
                         _Float16* __restrict__ Phm, _Float16* __restrict__ Plm,
                         const int* __restrict__ b2bm, const int* __restrict__ qrw_m,
                         const int* __restrict__ meta, int mmod) {
  const int Nb = meta[2 * mmod], nQ = meta[2 * mmod + 1];
  const int q = blockIdx.x;
  if (q >= nQ) return;
  const int t = threadIdx.x;
  __shared__ float wsh[3];
  __shared__ int idsh[3];
  if (t < 64) {
    const int nbblk = (Nb + 127) >> 7;
    float v0 = -INFINITY, v1 = -INFINITY, v2 = -INFINITY;
    int i0 = 0x7fffffff, i1 = 0x7fffffff, i2 = 0x7fffffff;
    for (int b = t; b < nbblk; b += 64) {
      const size_t o = ((size_t)q * 64 + b) * 3;
      upd3(cvals[o + 0], cidx[o + 0], v0, i0, v1, i1, v2, i2);
      upd3(cvals[o + 1], cidx[o + 1], v0, i0, v1, i1, v2, i2);
      upd3(cvals[o + 2], cidx[o + 2], v0, i0, v1, i1, v2, i2);
    }
#pragma unroll
    for (int mk = 1; mk <= 32; mk <<= 1) {
      float b0 = __shfl_xor(v0, mk, 64), b1 = __shfl_xor(v1, mk, 64), b2 = __shfl_xor(v2, mk, 64);
      int j0 = __shfl_xor(i0, mk, 64), j1 = __shfl_xor(i1, mk, 64), j2 = __shfl_xor(i2, mk, 64);
      merge3(v0, i0, v1, i1, v2, i2, b0, j0, b1, j1, b2, j2);
    }
    if (t == 0) {
      if (v0 == -INFINITY) {
        wsh[0] = wsh[1] = wsh[2] = 0.f; idsh[0] = idsh[1] = idsh[2] = 0;
      } else {
        const float e1w = (v1 == -INFINITY) ? 0.f : expf(v1 - v0);
        const float e2w = (v2 == -INFINITY) ? 0.f : expf(v2 - v0);
        const float inv = 1.f / (1.f + e1w + e2w);
        wsh[0] = inv; wsh[1] = e1w * inv; wsh[2] = e2w * inv;
        idsh[0] = i0;
        idsh[1] = (v1 == -INFINITY) ? i0 : i1;
        idsh[2] = (v2 == -INFINITY) ? i0 : i2;
      }
    }
  }
  __syncthreads();
  const float w0 = wsh[0], w1 = wsh[1], w2 = wsh[2];
  const size_t r0 = (size_t)b2bm[idsh[0]] * DDIM, r1 = (size_t)b2bm[idsh[1]] * DDIM,
               r2 = (size_t)b2bm[idsh[2]] * DDIM;
  const int e = t * 4;
  f16x4 h0 = *(const f16x4*)&Phm[r0 + e], l0 = *(const f16x4*)&Plm[r0 + e];
  f16x4 h1v = *(const f16x4*)&Phm[r1 + e], l1 = *(const f16x4*)&Plm[r1 + e];
  f16x4 h2 = *(const f16x4*)&Phm[r2 + e], l2 = *(const f16x4*)&Plm[r2 + e];
  const size_t qoffp = (size_t)qrw_m[q] * DDIM + e;
  f16x4 oh, ol;
#pragma unroll
  for (int i = 0; i < 4; ++i) {
    float a = (float)h0[i] + (float)l0[i] * LO_INV;
    float b = (float)h1v[i] + (float)l1[i] * LO_INV;
    float c = (float)h2[i] + (float)l2[i] * LO_INV;
    float o = w0 * a + w1 * b + w2 * c;
    oh[i] = (_Float16)o;
    ol[i] = (_Float16)((o - (float)oh[i]) * LO_SCALE);
  }
  *(f16x4*)&Phm[qoffp] = oh;
  *(f16x4*)&Plm[qoffp] = ol;
}

// ---- MFMA fp16 GEMM: H = relu(concat(P hi-planes) @ W1 + b1), fp16 out -----
__launch_bounds__(256, 2)
__global__ void gemm_h1_mfma(const _Float16* __restrict__ P, const _Float16* __restrict__ W1t,
                             const float* __restrict__ bias, _Float16* __restrict__ H) {
  const int K = 3072;
  __shared__ __align__(16) _Float16 Abuf[128 * 64];
  __shared__ __align__(16) _Float16 Bbuf[128 * 64];
  const int t = threadIdx.x;
  const int w = t >> 6, ln = t & 63;
  const int n0 = blockIdx.x * 128, m0 = blockIdx.y * 128;
  const int moff = (w & 1) * 64, noff = (w >> 1) * 64;
  const int lq = ln >> 4, lr = ln & 15;

  size_t aoff[4]; const _Float16* bs[4];
  _Float16* ad[4]; _Float16* bd[4];
#pragma unroll
  for (int p = 0; p < 4; ++p) {
    int r = p * 32 + w * 8 + (ln >> 3);
    int l = (ln & 7) ^ (r & 7);
    aoff[p] = ((size_t)(m0 + r) << 10) + (size_t)(l * 8);
    bs[p] = W1t + (size_t)(n0 + r) * K + l * 8;
    ad[p] = &Abuf[(p * 32 + w * 8) * 64];
    bd[p] = &Bbuf[(p * 32 + w * 8) * 64];
  }

  f32x4 acc[4][4] = {};

  for (int k0 = 0; k0 < K; k0 += 64) {
    const _Float16* aplane = P + ((size_t)(k0 >> 10) * 2) * PSZ + (k0 & 1023);
#pragma unroll
    for (int p = 0; p < 4; ++p) {
      gload_lds16(aplane + aoff[p], ad[p]);
      gload_lds16(bs[p] + k0, bd[p]);
    }
    __syncthreads();
#pragma unroll
    for (int ks = 0; ks < 2; ++ks) {
      f16x8 a[4];
#pragma unroll
      for (int mt = 0; mt < 4; ++mt) {
        int r = moff + mt * 16 + lr;
        a[mt] = *(f16x8*)&Abuf[r * 64 + ((ks * 4 + lq) ^ (r & 7)) * 8];
      }
#pragma unroll
      for (int nt = 0; nt < 4; ++nt) {
        int r = noff + nt * 16 + lr;
        f16x8 b = *(f16x8*)&Bbuf[r * 64 + ((ks * 4 + lq) ^ (r & 7)) * 8];
#pragma unroll
        for (int mt = 0; mt < 4; ++mt)
          acc[mt][nt] = __builtin_amdgcn_mfma_f32_16x16x32_f16(a[mt], b, acc[mt][nt], 0, 0, 0);
      }
    }
    __syncthreads();
  }
#pragma unroll
  for (int nt = 0; nt < 4; ++nt) {
    int col = n0 + noff + nt * 16 + lr;
    float bv = bias[col];
#pragma unroll
    for (int mt = 0; mt < 4; ++mt) {
      int row = m0 + moff + mt * 16 + lq * 4;
#pragma unroll
      for (int r = 0; r < 4; ++r)
        H[(size_t)(row + r) * DDIM + col] = (_Float16)fmaxf(acc[mt][nt][r] + bv, 0.f);
    }
  }
}

// ---------------- bank build (fused norm), tail-zero, final -----------------
__global__ void build_bnk(const _Float16* __restrict__ Phm, const _Float16* __restrict__ Plm,
                          const int* __restrict__ b2bm, const int* __restrict__ meta,
                          int mmod, _Float16* __restrict__ bnh, _Float16* __restrict__ bnl) {
  const int j = blockIdx.x, t = threadIdx.x;
  const int Nb = meta[2 * mmod];
  const size_t o = (size_t)j * DDIM + t * 4;
  if (j >= Nb) {
    *(f16x4*)&bnh[o] = (f16x4)0;
    *(f16x4*)&bnl[o] = (f16x4)0;
    return;
  }
  const int b = b2bm[j];
  f16x4 h = *(const f16x4*)&Phm[(size_t)b * DDIM + t * 4];
  f16x4 l = *(const f16x4*)&Plm[(size_t)b * DDIM + t * 4];
  float v[4]; float s = 0.f;
#pragma unroll
  for (int i = 0; i < 4; ++i) {
    v[i] = (float)h[i] + (float)l[i] * LO_INV;
    s += v[i] * v[i];
  }
  for (int ofs = 32; ofs > 0; ofs >>= 1) s += __shfl_down(s, ofs, 64);
  __shared__ float ls[4];
  if ((t & 63) == 0) ls[t >> 6] = s;
  __syncthreads();
  const float inv = 1.0f / fmaxf(sqrtf(ls[0] + ls[1] + ls[2] + ls[3]), 1e-8f);
  f16x4 hv, lv;
#pragma unroll
  for (int i = 0; i < 4; ++i) {
    float x = v[i] * inv;
    hv[i] = (_Float16)x;
    lv[i] = (_Float16)((x - (float)hv[i]) * LO_SCALE);
  }
  *(f16x4*)&bnh[o] = hv;
  *(f16x4*)&bnl[o] = lv;
}

__global__ void zero_tail(const int* __restrict__ miss, const int* __restrict__ meta,
                          _Float16* __restrict__ P) {
  const int row = blockIdx.x, m = blockIdx.y;
  if (miss[row] != m + 1) return;
  if (row < meta[2 * m]) return;
  f16x4 z = (f16x4)0;
  const size_t o = (size_t)row * DDIM + threadIdx.x * 4;
  *(f16x4*)&P[(size_t)(2 * m) * PSZ + o] = z;
  *(f16x4*)&P[(size_t)(2 * m + 1) * PSZ + o] = z;
}

__global__ void out_kernel(const _Float16* __restrict__ h1, const float* __restrict__ w2,
                           const float* __restrict__ b2p, float* __restrict__ out) {
  const int row = blockIdx.x, t = threadIdx.x;
  f16x4 h = *(const f16x4*)&h1[(size_t)row * DDIM + t * 4];
  float4 w = *(const float4*)&w2[t * 4];
  float s = (float)h[0] * w.x + (float)h[1] * w.y + (float)h[2] * w.z + (float)h[3] * w.w;
  for (int o = 32; o > 0; o >>= 1) s += __shfl_down(s, o, 64);
  __shared__ float ls[4];
  if ((t & 63) == 0) ls[t >> 6] = s;
  __syncthreads();
  if (t == 0) out[row] = ls[0] + ls[1] + ls[2] + ls[3] + b2p[0];
}

extern "C" void kernel_launch(void* const* d_in, const int* in_sizes, int n_in,
                              void* d_out, int out_size, void* d_ws, size_t ws_size,
                              hipStream_t stream) {
  const float* xs[3] = {(const float*)d_in[0], (const float*)d_in[1], (const float*)d_in[2]};
  const int* miss = (const int*)d_in[3];
  const float* Wm[3] = {(const float*)d_in[4], (const float*)d_in[6], (const float*)d_in[8]};
  const float* bm[3] = {(const float*)d_in[5], (const float*)d_in[7], (const float*)d_in[9]};
  const float* W1 = (const float*)d_in[10];
  const float* b1 = (const float*)d_in[11];
  const float* W2 = (const float*)d_in[12];
  const float* b2v = (const float*)d_in[13];

  char* base = (char*)d_ws;
  size_t off = 0;
  auto carve = [&](size_t bytes) -> void* {
    void* p = base + off;
    off += (bytes + 255) & ~(size_t)255;
    return p;
  };
  int*   meta  = (int*)carve(256);
  int*   b2b   = (int*)carve((size_t)3 * NB_ROWS * sizeof(int));
  int*   qrw   = (int*)carve((size_t)3 * 4096 * sizeof(int));
  _Float16* P = (_Float16*)carve((size_t)6 * PSZ * sizeof(_Float16));  // 96 MB
  char* R1 = (char*)carve((size_t)72 * 1024 * 1024);
  if (off > ws_size) return;  // ~168.1 MB

  const size_t MB = 1024 * 1024;
  // phase 1 aliases:
  _Float16* A2h = (_Float16*)R1;                 // 32 MB
  _Float16* A2l = (_Float16*)(R1 + 32 * MB);     // 32 MB
  _Float16* wth = (_Float16*)(R1 + 64 * MB);     // 4 MB
  _Float16* wtl = (_Float16*)(R1 + 68 * MB);     // 4 MB
  // phase 2 aliases:
  _Float16* bnkh = (_Float16*)R1;                // 16 MB
  _Float16* bnkl = (_Float16*)(R1 + 16 * MB);    // 16 MB
  _Float16* Qh   = (_Float16*)(R1 + 32 * MB);    // 8 MB (4096 x 1024 f16)
  _Float16* Ql   = (_Float16*)(R1 + 40 * MB);    // 8 MB
  float*    cvals = (float*)(R1 + 48 * MB);      // 3 MB (4096 x 64 x 3)
  int*      cidx  = (int*)(R1 + 52 * MB);        // 3 MB
  // phase 3 aliases:
  _Float16* W1t   = (_Float16*)R1;               // 6 MB
  _Float16* h1f16 = (_Float16*)(R1 + 32 * MB);   // 16 MB

  scan_kernel<<<dim3(3), dim3(256), 0, stream>>>(miss, meta, b2b, qrw);

  for (int m = 0; m < 3; ++m) {
    tsplit<<<dim3(64, 32), dim3(32, 8), 0, stream>>>(Wm[m], wth, wtl, 2048, 1024);
    xsplit<<<dim3(8192), dim3(256), 0, stream>>>(xs[m], A2h, A2l);
    gemm_proj_mfma<<<dim3(8, 64), dim3(256), 0, stream>>>(
        A2h, A2l, wth, wtl, bm[m], P + (size_t)(2 * m) * PSZ, P + (size_t)(2 * m + 1) * PSZ);
  }

  for (int m = 0; m < 3; ++m) {
    build_bnk<<<dim3(NB_ROWS), dim3(256), 0, stream>>>(
        P + (size_t)(2 * m) * PSZ, P + (size_t)(2 * m + 1) * PSZ,
        b2b + m * NB_ROWS, meta, m, bnkh, bnkl);
    qgather<<<dim3(4096), dim3(256), 0, stream>>>(
        bnkh, bnkl, qrw + m * 4096, meta, m, Qh, Ql);
    gemm_sim_topk<<<dim3(64, 32), dim3(256), 0, stream>>>(
        bnkh, bnkl, Qh, Ql, meta, miss, m, cvals, cidx);
    knn_fill<<<dim3(4096), dim3(256), 0, stream>>>(
        cvals, cidx, P + (size_t)(2 * m) * PSZ, P + (size_t)(2 * m + 1) * PSZ,
        b2b + m * NB_ROWS, qrw + m * 4096, meta, m);
  }

  zero_tail<<<dim3(NB_ROWS, 3), dim3(256), 0, stream>>>(miss, meta, P);
  tsplit<<<dim3(96, 32), dim3(32, 8), 0, stream>>>(W1, W1t, (_Float16*)nullptr, 3072, 1024);
  gemm_h1_mfma<<<dim3(8, 64), dim3(256), 0, stream>>>(P, W1t, b1, h1f16);
  out_kernel<<<dim3(NB_ROWS), dim3(256), 0, stream>>>(h1f16, W2, b2v, (float*)d_out);
}

// Round 7
// 1091.994 us; speedup vs baseline: 1.0613x; 1.0613x over previous
//
#include <hip/hip_runtime.h>
#include <math.h>

#define NB_ROWS 8192
#define DDIM 1024
#define PSZ ((size_t)NB_ROWS * DDIM)

typedef _Float16 f16x8 __attribute__((ext_vector_type(8)));
typedef _Float16 f16x4 __attribute__((ext_vector_type(4)));
typedef float f32x4 __attribute__((ext_vector_type(4)));

#define LO_SCALE 1024.0f
#define LO_INV (1.0f / 1024.0f)

__device__ __forceinline__ void gload_lds16(const void* g, void* l) {
  __builtin_amdgcn_global_load_lds((const __attribute__((address_space(1))) void*)g,
                                   (__attribute__((address_space(3))) void*)l, 16, 0, 0);
}

// LDS byte offset of a __shared__ pointer (AS3 pointers are 32-bit offsets)
__device__ __forceinline__ unsigned lds_off(const void* p) {
  return (unsigned)(size_t)(const __attribute__((address_space(3))) void*)p;
}

// opaque ds_read_b128: invisible to compiler alias analysis, so no conservative
// vmcnt(0) is inserted between in-flight global_load_lds and this read.
// MUST be followed by s_waitcnt lgkmcnt(0) + sched_barrier(0) before use (rule #18).
__device__ __forceinline__ f16x8 ds_read128(unsigned addr) {
  f32x4 d;
  asm volatile("ds_read_b128 %0, %1" : "=v"(d) : "v"(addr));
  union { f32x4 f; f16x8 h; } u;
  u.f = d;
  return u.h;
}

__device__ __forceinline__ bool pair_better(float s, int j, float v, int i) {
  return (s > v) || (s == v && j < i);
}

__device__ __forceinline__ void upd3(float s, int jj, float& v0, int& i0,
                                     float& v1, int& i1, float& v2, int& i2) {
  if (pair_better(s, jj, v0, i0)) { v2 = v1; i2 = i1; v1 = v0; i1 = i0; v0 = s; i0 = jj; }
  else if (pair_better(s, jj, v1, i1)) { v2 = v1; i2 = i1; v1 = s; i1 = jj; }
  else if (pair_better(s, jj, v2, i2)) { v2 = s; i2 = jj; }
}

// merge sorted triple (v) with sorted triple (b) -> sorted top-3 in (v)
__device__ __forceinline__ void merge3(float& v0, int& i0, float& v1, int& i1,
                                       float& v2, int& i2, float b0, int jb0,
                                       float b1, int jb1, float b2, int jb2) {
  float r0, r1, r2; int q0, q1, q2;
  if (pair_better(v0, i0, b0, jb0)) {
    r0 = v0; q0 = i0;
    if (pair_better(v1, i1, b0, jb0)) {
      r1 = v1; q1 = i1;
      if (pair_better(v2, i2, b0, jb0)) { r2 = v2; q2 = i2; } else { r2 = b0; q2 = jb0; }
    } else {
      r1 = b0; q1 = jb0;
      if (pair_better(v1, i1, b1, jb1)) { r2 = v1; q2 = i1; } else { r2 = b1; q2 = jb1; }
    }
  } else {
    r0 = b0; q0 = jb0;
    if (pair_better(v0, i0, b1, jb1)) {
      r1 = v0; q1 = i0;
      if (pair_better(v1, i1, b1, jb1)) { r2 = v1; q2 = i1; } else { r2 = b1; q2 = jb1; }
    } else {
      r1 = b1; q1 = jb1;
      if (pair_better(v0, i0, b2, jb2)) { r2 = v0; q2 = i0; } else { r2 = b2; q2 = jb2; }
    }
  }
  v0 = r0; i0 = q0; v1 = r1; i1 = q1; v2 = r2; i2 = q2;
}

// ---------------- scan: bank2batch + query list per modality ----------------
__global__ void scan_kernel(const int* __restrict__ miss, int* __restrict__ meta,
                            int* __restrict__ b2b, int* __restrict__ qrw) {
  const int m = blockIdx.x, t = threadIdx.x, tmod = m + 1;
  __shared__ int cnt[256];
  const int base = t * 32;
  int c = 0;
  for (int i = 0; i < 32; ++i) c += (miss[base + i] != tmod) ? 1 : 0;
  cnt[t] = c; __syncthreads();
  for (int s = 1; s < 256; s <<= 1) {
    int v = (t >= s) ? cnt[t - s] : 0;
    __syncthreads();
    cnt[t] += v;
    __syncthreads();
  }
  const int Nb = cnt[255];
  int pos = cnt[t] - c;
  for (int i = 0; i < 32; ++i) {
    int r = base + i;
    if (miss[r] != tmod) b2b[m * NB_ROWS + (pos++)] = r;
  }
  __syncthreads();
  int q = 0;
  for (int i = 0; i < 32; ++i) {
    int r = base + i;
    q += (miss[r] == tmod && r < Nb) ? 1 : 0;
  }
  cnt[t] = q; __syncthreads();
  for (int s = 1; s < 256; s <<= 1) {
    int v = (t >= s) ? cnt[t - s] : 0;
    __syncthreads();
    cnt[t] += v;
    __syncthreads();
  }
  int nQ = cnt[255];
  if (nQ > 4096) nQ = 4096;
  int qpos = cnt[t] - q;
  for (int i = 0; i < 32; ++i) {
    int r = base + i;
    if (miss[r] == tmod && r < Nb && qpos < 4096) qrw[m * 4096 + (qpos++)] = r;
  }
  for (int i = nQ + t; i < 4096; i += 256) qrw[m * 4096 + i] = 0;  // pad tail
  if (t == 0) { meta[2 * m] = Nb; meta[2 * m + 1] = nQ; }
}

// ------------- transpose + fp16 split body: W[K][N] -> Th/Tl[N][K] ----------
__device__ __forceinline__ void tsplit_body(const float* __restrict__ W,
                                            _Float16* __restrict__ Th,
                                            _Float16* __restrict__ Tl,
                                            int K, int N, int bx, int by, int t) {
  __shared__ float tile[32][33];
  const int k0 = bx * 32, n0 = by * 32;
  const int tx = t & 31, ty = t >> 5;
  for (int i = ty; i < 32; i += 8)
    tile[i][tx] = W[(size_t)(k0 + i) * N + n0 + tx];
  __syncthreads();
  for (int i = ty; i < 32; i += 8) {
    float v = tile[tx][i];
    _Float16 h = (_Float16)v;
    Th[(size_t)(n0 + i) * K + k0 + tx] = h;
    if (Tl) Tl[(size_t)(n0 + i) * K + k0 + tx] = (_Float16)((v - (float)h) * LO_SCALE);
  }
}

__device__ __forceinline__ f16x8 cvt_hi8(float4 a, float4 b) {
  f16x8 r;
  r[0] = (_Float16)a.x; r[1] = (_Float16)a.y; r[2] = (_Float16)a.z; r[3] = (_Float16)a.w;
  r[4] = (_Float16)b.x; r[5] = (_Float16)b.y; r[6] = (_Float16)b.z; r[7] = (_Float16)b.w;
  return r;
}
__device__ __forceinline__ f16x8 cvt_lo8(float4 a, float4 b, f16x8 h) {
  f16x8 r;
  r[0] = (_Float16)((a.x - (float)h[0]) * LO_SCALE);
  r[1] = (_Float16)((a.y - (float)h[1]) * LO_SCALE);
  r[2] = (_Float16)((a.z - (float)h[2]) * LO_SCALE);
  r[3] = (_Float16)((a.w - (float)h[3]) * LO_SCALE);
  r[4] = (_Float16)((b.x - (float)h[4]) * LO_SCALE);
  r[5] = (_Float16)((b.y - (float)h[5]) * LO_SCALE);
  r[6] = (_Float16)((b.z - (float)h[6]) * LO_SCALE);
  r[7] = (_Float16)((b.w - (float)h[7]) * LO_SCALE);
  return r;
}

__device__ __forceinline__ void xsplit_body(const float* __restrict__ X,
                                            _Float16* __restrict__ Ah,
                                            _Float16* __restrict__ Al, int b, int t) {
  const size_t idx = ((size_t)b * 256 + t) * 8;
  float4 f0 = *(const float4*)(X + idx);
  float4 f1 = *(const float4*)(X + idx + 4);
  f16x8 hi = cvt_hi8(f0, f1);
  f16x8 lo = cvt_lo8(f0, f1, hi);
  *(f16x8*)(Ah + idx) = hi;
  *(f16x8*)(Al + idx) = lo;
}

// ---- fused per-modality prep: tsplit(Wm) [2048 blocks] + xsplit(x) [8192] --
__global__ void prep_kernel(const float* __restrict__ W, _Float16* __restrict__ Th,
                            _Float16* __restrict__ Tl, const float* __restrict__ X,
                            _Float16* __restrict__ Ah, _Float16* __restrict__ Al) {
  const int b = blockIdx.x, t = threadIdx.x;
  if (b < 2048) tsplit_body(W, Th, Tl, 2048, 1024, b & 63, b >> 6, t);
  else          xsplit_body(X, Ah, Al, b - 2048, t);
}

// ---- MFMA split GEMM (round-2 proven inner loop + XCD-chunked swizzle):
//      proj = A(hi/lo)[8192,2048] @ Bt(hi/lo)[1024,2048]^T + bias
__launch_bounds__(256, 2)
__global__ void gemm_proj_mfma(const _Float16* __restrict__ Ah, const _Float16* __restrict__ Al,
                               const _Float16* __restrict__ Bh, const _Float16* __restrict__ Bl,
                               const float* __restrict__ bias,
                               _Float16* __restrict__ Ph, _Float16* __restrict__ Pl) {
  const int K = 2048;
  __shared__ __align__(16) _Float16 Abuf[128 * 64];
  __shared__ __align__(16) _Float16 Bbuf[128 * 64];
  const int t = threadIdx.x;
  const int w = t >> 6, ln = t & 63;
  // XCD-chunked bijective swizzle: grid 512 works, XCD x serves works with
  // pos%8==x -> wk in [64x,64x+64): 8 consecutive m-panels, A-panel fetched
  // once per L2 instead of 8x across XCDs.
  const int pos = blockIdx.y * 8 + blockIdx.x;
  const int wk = (pos & 7) * 64 + (pos >> 3);
  const int n0 = (wk & 7) * 128, m0 = (wk >> 3) * 128;
  const int moff = (w & 1) * 64, noff = (w >> 1) * 64;
  const int lq = ln >> 4, lr = ln & 15;

  const _Float16* as[4]; const _Float16* bs[4];
  _Float16* ad[4]; _Float16* bd[4];
#pragma unroll
  for (int p = 0; p < 4; ++p) {
    int r = p * 32 + w * 8 + (ln >> 3);
    int l = (ln & 7) ^ (r & 7);
    as[p] = (l < 4) ? (Ah + (size_t)(m0 + r) * K + l * 8)
                    : (Al + (size_t)(m0 + r) * K + (l - 4) * 8);
    bs[p] = (l < 4) ? (Bh + (size_t)(n0 + r) * K + l * 8)
                    : (Bl + (size_t)(n0 + r) * K + (l - 4) * 8);
    ad[p] = &Abuf[(p * 32 + w * 8) * 64];
    bd[p] = &Bbuf[(p * 32 + w * 8) * 64];
  }

  f32x4 acc[4][4] = {};
  f32x4 acc2[4][4] = {};

  for (int k0 = 0; k0 < K; k0 += 32) {
#pragma unroll
    for (int p = 0; p < 4; ++p) {
      gload_lds16(as[p] + k0, ad[p]);
      gload_lds16(bs[p] + k0, bd[p]);
    }
    __syncthreads();
    f16x8 ahi[4], alo[4];
#pragma unroll
    for (int mt = 0; mt < 4; ++mt) {
      int r = moff + mt * 16 + lr;
      ahi[mt] = *(f16x8*)&Abuf[r * 64 + ((lq) ^ (r & 7)) * 8];
      alo[mt] = *(f16x8*)&Abuf[r * 64 + ((lq + 4) ^ (r & 7)) * 8];
    }
#pragma unroll
    for (int nt = 0; nt < 4; ++nt) {
      int r = noff + nt * 16 + lr;
      f16x8 bhi = *(f16x8*)&Bbuf[r * 64 + ((lq) ^ (r & 7)) * 8];
      f16x8 blo = *(f16x8*)&Bbuf[r * 64 + ((lq + 4) ^ (r & 7)) * 8];
#pragma unroll
      for (int mt = 0; mt < 4; ++mt) {
        acc[mt][nt]  = __builtin_amdgcn_mfma_f32_16x16x32_f16(ahi[mt], bhi, acc[mt][nt], 0, 0, 0);
        acc2[mt][nt] = __builtin_amdgcn_mfma_f32_16x16x32_f16(ahi[mt], blo, acc2[mt][nt], 0, 0, 0);
        acc2[mt][nt] = __builtin_amdgcn_mfma_f32_16x16x32_f16(alo[mt], bhi, acc2[mt][nt], 0, 0, 0);
      }
    }
    __syncthreads();
  }
#pragma unroll
  for (int nt = 0; nt < 4; ++nt) {
    int col = n0 + noff + nt * 16 + lr;
    float bv = bias[col];
#pragma unroll
    for (int mt = 0; mt < 4; ++mt) {
      int row = m0 + moff + mt * 16 + lq * 4;
#pragma unroll
      for (int r = 0; r < 4; ++r) {
        float v = acc[mt][nt][r] + acc2[mt][nt][r] * LO_INV + bv;
        _Float16 h = (_Float16)v;
        Ph[(size_t)(row + r) * DDIM + col] = h;
        Pl[(size_t)(row + r) * DDIM + col] = (_Float16)((v - (float)h) * LO_SCALE);
      }
    }
  }
}

// top-3 of this lane-group's 64 columns for one physical row (16 lanes x 4 vals)
__device__ __forceinline__ void sel3_row(const float* bv, const int* bi,
                                         float& v0, int& i0, float& v1, int& i1,
                                         float& v2, int& i2) {
  float lm; int li;
  // pass 0
  lm = -INFINITY; li = 0x7fffffff;
#pragma unroll
  for (int nt = 0; nt < 4; ++nt)
    if (pair_better(bv[nt], bi[nt], lm, li)) { lm = bv[nt]; li = bi[nt]; }
#pragma unroll
  for (int mk = 1; mk <= 8; mk <<= 1) {
    float ov = __shfl_xor(lm, mk, 64); int oi = __shfl_xor(li, mk, 64);
    if (pair_better(ov, oi, lm, li)) { lm = ov; li = oi; }
  }
  v0 = lm; i0 = li;
  // pass 1 (exclude i0 by index; indices are unique)
  lm = -INFINITY; li = 0x7fffffff;
#pragma unroll
  for (int nt = 0; nt < 4; ++nt)
    if (bi[nt] != i0 && pair_better(bv[nt], bi[nt], lm, li)) { lm = bv[nt]; li = bi[nt]; }
#pragma unroll
  for (int mk = 1; mk <= 8; mk <<= 1) {
    float ov = __shfl_xor(lm, mk, 64); int oi = __shfl_xor(li, mk, 64);
    if (pair_better(ov, oi, lm, li)) { lm = ov; li = oi; }
  }
  v1 = lm; i1 = li;
  // pass 2 (exclude i0, i1)
  lm = -INFINITY; li = 0x7fffffff;
#pragma unroll
  for (int nt = 0; nt < 4; ++nt)
    if (bi[nt] != i0 && bi[nt] != i1 && pair_better(bv[nt], bi[nt], lm, li)) { lm = bv[nt]; li = bi[nt]; }
#pragma unroll
  for (int mk = 1; mk <= 8; mk <<= 1) {
    float ov = __shfl_xor(lm, mk, 64); int oi = __shfl_xor(li, mk, 64);
    if (pair_better(ov, oi, lm, li)) { lm = ov; li = oi; }
  }
  v2 = lm; i2 = li;
}

// ---- compact query gather: Q[i] = bank[qrw[i]] (contiguous A for sim) ------
__global__ void qgather(const _Float16* __restrict__ bnh, const _Float16* __restrict__ bnl,
                        const int* __restrict__ qrw_m, const int* __restrict__ meta, int mmod,
                        _Float16* __restrict__ Qh, _Float16* __restrict__ Ql) {
  const int q = blockIdx.x, t = threadIdx.x;
  const int nQ = meta[2 * mmod + 1];
  const size_t o = (size_t)q * DDIM + t * 4;
  if (q >= nQ) {
    *(f16x4*)&Qh[o] = (f16x4)0;
    *(f16x4*)&Ql[o] = (f16x4)0;
    return;
  }
  const size_t s = (size_t)qrw_m[q] * DDIM + t * 4;
  *(f16x4*)&Qh[o] = *(const f16x4*)&bnh[s];
  *(f16x4*)&Ql[o] = *(const f16x4*)&bnl[s];
}

// ---- MFMA split sim + fused masked top-3, dbuf + asm-ds_read overlap -------
// (round-5 proven form: 222 -> 134 us). Identity block mapping keeps each
// XCD's B-panels L2-resident.
__launch_bounds__(256, 2)
__global__ void gemm_sim_topk(const _Float16* __restrict__ bh, const _Float16* __restrict__ bl,
                              const _Float16* __restrict__ Qh, const _Float16* __restrict__ Ql,
                              const int* __restrict__ meta, const int* __restrict__ miss,
                              int mmod, float* __restrict__ cvals, int* __restrict__ cidx) {
  const int Nb = meta[2 * mmod], nQ = meta[2 * mmod + 1];
  const int n0 = blockIdx.x * 128, m0 = blockIdx.y * 128;
  if (m0 >= nQ || n0 >= Nb) return;
  __shared__ __align__(16) _Float16 Abuf[2][128 * 64];
  __shared__ __align__(16) _Float16 Bbuf[2][128 * 64];
  __shared__ float csv[128][2][3];
  __shared__ int   csi[128][2][3];
  const int t = threadIdx.x;
  const int w = t >> 6, ln = t & 63;
  const int moff = (w & 1) * 64, noff = (w >> 1) * 64;
  const int lq = ln >> 4, lr = ln & 15;

  const _Float16* as[4]; const _Float16* bs[4]; int doff[4];
#pragma unroll
  for (int p = 0; p < 4; ++p) {
    int r = p * 32 + w * 8 + (ln >> 3);
    int l = (ln & 7) ^ (r & 7);
    as[p] = (l < 4) ? (Qh + (size_t)(m0 + r) * DDIM + l * 8)
                    : (Ql + (size_t)(m0 + r) * DDIM + (l - 4) * 8);
    bs[p] = (l < 4) ? (bh + (size_t)(n0 + r) * DDIM + l * 8)
                    : (bl + (size_t)(n0 + r) * DDIM + (l - 4) * 8);
    doff[p] = (p * 32 + w * 8) * 64;
  }
  unsigned aoh[4], aol[4], boh[4], bol[4];
#pragma unroll
  for (int mt = 0; mt < 4; ++mt) {
    int r = moff + mt * 16 + lr;
    aoh[mt] = (unsigned)(r * 64 + ((lq) ^ (r & 7)) * 8) * 2u;
    aol[mt] = (unsigned)(r * 64 + ((lq + 4) ^ (r & 7)) * 8) * 2u;
    int rn = noff + mt * 16 + lr;
    boh[mt] = (unsigned)(rn * 64 + ((lq) ^ (rn & 7)) * 8) * 2u;
    bol[mt] = (unsigned)(rn * 64 + ((lq + 4) ^ (rn & 7)) * 8) * 2u;
  }
  const unsigned abase = lds_off(&Abuf[0][0]);
  const unsigned bbase = lds_off(&Bbuf[0][0]);

  f32x4 acc[4][4] = {};
  f32x4 acc2[4][4] = {};

  // prologue: stage k=0 into buffer 0
#pragma unroll
  for (int p = 0; p < 4; ++p) {
    gload_lds16(as[p], &Abuf[0][doff[p]]);
    gload_lds16(bs[p], &Bbuf[0][doff[p]]);
  }
  __syncthreads();

  unsigned cursel = 0;
  for (int k0 = 0; k0 < DDIM; k0 += 32) {
    if (k0 + 32 < DDIM) {
      const unsigned ns = cursel ^ 1u;
#pragma unroll
      for (int p = 0; p < 4; ++p) {
        gload_lds16(as[p] + k0 + 32, &Abuf[ns][doff[p]]);
        gload_lds16(bs[p] + k0 + 32, &Bbuf[ns][doff[p]]);
      }
    }
    const unsigned ab = abase + cursel * 16384u;
    const unsigned bb = bbase + cursel * 16384u;
    f16x8 ahi[4], alo[4], bhi[4], blo[4];
#pragma unroll
    for (int mt = 0; mt < 4; ++mt) { ahi[mt] = ds_read128(ab + aoh[mt]); alo[mt] = ds_read128(ab + aol[mt]); }
#pragma unroll
    for (int nt = 0; nt < 4; ++nt) { bhi[nt] = ds_read128(bb + boh[nt]); blo[nt] = ds_read128(bb + bol[nt]); }
    asm volatile("s_waitcnt lgkmcnt(0)" ::: "memory");
    __builtin_amdgcn_sched_barrier(0);
#pragma unroll
    for (int nt = 0; nt < 4; ++nt)
#pragma unroll
      for (int mt = 0; mt < 4; ++mt) {
        acc[mt][nt]  = __builtin_amdgcn_mfma_f32_16x16x32_f16(ahi[mt], bhi[nt], acc[mt][nt], 0, 0, 0);
        acc2[mt][nt] = __builtin_amdgcn_mfma_f32_16x16x32_f16(ahi[mt], blo[nt], acc2[mt][nt], 0, 0, 0);
        acc2[mt][nt] = __builtin_amdgcn_mfma_f32_16x16x32_f16(alo[mt], bhi[nt], acc2[mt][nt], 0, 0, 0);
      }
    __syncthreads();
    cursel ^= 1u;
  }

  // fused epilogue: per-row masked top-3 from accumulators (no S write)
  bool okc[4]; int colg[4];
#pragma unroll
  for (int nt = 0; nt < 4; ++nt) {
    int col = n0 + noff + nt * 16 + lr;
    colg[nt] = col;
    okc[nt] = (col < Nb) && (miss[col] != mmod + 1);  // col_valid, batch-indexed (source bug kept)
  }
  const int nh = w >> 1;
#pragma unroll
  for (int mt = 0; mt < 4; ++mt) {
#pragma unroll
    for (int r = 0; r < 4; ++r) {
      float bv[4];
#pragma unroll
      for (int nt = 0; nt < 4; ++nt)
        bv[nt] = okc[nt] ? (acc[mt][nt][r] + acc2[mt][nt][r] * LO_INV) : -INFINITY;
      float v0, v1, v2; int i0, i1, i2;
      sel3_row(bv, colg, v0, i0, v1, i1, v2, i2);
      if (lr == 0) {
        int row = moff + mt * 16 + lq * 4 + r;
        csv[row][nh][0] = v0; csi[row][nh][0] = i0;
        csv[row][nh][1] = v1; csi[row][nh][1] = i1;
        csv[row][nh][2] = v2; csi[row][nh][2] = i2;
      }
    }
  }
  __syncthreads();
  if (t < 128) {
    float v0 = -INFINITY, v1 = -INFINITY, v2 = -INFINITY;
    int i0 = 0x7fffffff, i1 = 0x7fffffff, i2 = 0x7fffffff;
#pragma unroll
    for (int h = 0; h < 2; ++h)
#pragma unroll
      for (int s = 0; s < 3; ++s)
        upd3(csv[t][h][s], csi[t][h][s], v0, i0, v1, i1, v2, i2);
    const size_t o = ((size_t)(m0 + t) * 64 + (size_t)(n0 >> 7)) * 3;
    cvals[o + 0] = v0; cidx[o + 0] = i0;
    cvals[o + 1] = v1; cidx[o + 1] = i1;
    cvals[o + 2] = v2; cidx[o + 2] = i2;
  }
}

// ---- knn fill body: merge candidates -> top-3 -> softmax-weighted fill -----
__device__ __forceinline__ void knn_body(const float* __restrict__ cvals,
                                         const int* __restrict__ cidx,
                                         _Float16* __restrict__ Phm, _Float16* __restrict__ Plm,
                                         const int* __restrict__ b2bm,
                                         const int* __restrict__ qrw_m,
                                         const int* __restrict__ meta, int mmod, int q) {
  const int Nb = meta[2 * mmod], nQ = meta[2 * mmod + 1];
  if (q >= nQ) return;
  const int t = threadIdx.x;
  __shared__ float wsh[3];
  __shared__ int idsh[3];
  if (t < 64) {
    const int nbblk = (Nb + 127) >> 7;
    float v0 = -INFINITY, v1 = -INFINITY, v2 = -INFINITY;
    int i0 = 0x7fffffff, i1 = 0x7fffffff, i2 = 0x7fffffff;
    for (int b = t; b < nbblk; b += 64) {
      const size_t o = ((size_t)q * 64 + b) * 3;
      upd3(cvals[o + 0], cidx[o + 0], v0, i0, v1, i1, v2, i2);
      upd3(cvals[o + 1], cidx[o + 1], v0, i0, v1, i1, v2, i2);
      upd3(cvals[o + 2], cidx[o + 2], v0, i0, v1, i1, v2, i2);
    }
#pragma unroll
    for (int mk = 1; mk <= 32; mk <<= 1) {
      float b0 = __shfl_xor(v0, mk, 64), b1 = __shfl_xor(v1, mk, 64), b2 = __shfl_xor(v2, mk, 64);
      int j0 = __shfl_xor(i0, mk, 64), j1 = __shfl_xor(i1, mk, 64), j2 = __shfl_xor(i2, mk, 64);
      merge3(v0, i0, v1, i1, v2, i2, b0, j0, b1, j1, b2, j2);
    }
    if (t == 0) {
      if (v0 == -INFINITY) {
        wsh[0] = wsh[1] = wsh[2] = 0.f; idsh[0] = idsh[1] = idsh[2] = 0;
      } else {
        const float e1w = (v1 == -INFINITY) ? 0.f : expf(v1 - v0);
        const float e2w = (v2 == -INFINITY) ? 0.f : expf(v2 - v0);
        const float inv = 1.f / (1.f + e1w + e2w);
        wsh[0] = inv; wsh[1] = e1w * inv; wsh[2] = e2w * inv;
        idsh[0] = i0;
        idsh[1] = (v1 == -INFINITY) ? i0 : i1;
        idsh[2] = (v2 == -INFINITY) ? i0 : i2;
      }
    }
  }
  __syncthreads();
  const float w0 = wsh[0], w1 = wsh[1], w2 = wsh[2];
  const size_t r0 = (size_t)b2bm[idsh[0]] * DDIM, r1 = (size_t)b2bm[idsh[1]] * DDIM,
               r2 = (size_t)b2bm[idsh[2]] * DDIM;
  const int e = t * 4;
  f16x4 h0 = *(const f16x4*)&Phm[r0 + e], l0 = *(const f16x4*)&Plm[r0 + e];
  f16x4 h1v = *(const f16x4*)&Phm[r1 + e], l1 = *(const f16x4*)&Plm[r1 + e];
  f16x4 h2 = *(const f16x4*)&Phm[r2 + e], l2 = *(const f16x4*)&Plm[r2 + e];
  const size_t qoffp = (size_t)qrw_m[q] * DDIM + e;
  f16x4 oh, ol;
#pragma unroll
  for (int i = 0; i < 4; ++i) {
    float a = (float)h0[i] + (float)l0[i] * LO_INV;
    float b = (float)h1v[i] + (float)l1[i] * LO_INV;
    float c = (float)h2[i] + (float)l2[i] * LO_INV;
    float o = w0 * a + w1 * b + w2 * c;
    oh[i] = (_Float16)o;
    ol[i] = (_Float16)((o - (float)oh[i]) * LO_SCALE);
  }
  *(f16x4*)&Phm[qoffp] = oh;
  *(f16x4*)&Plm[qoffp] = ol;
}

// ---- bank build body (fused norm) ------------------------------------------
__device__ __forceinline__ void bnk_body(const _Float16* __restrict__ Phm,
                                         const _Float16* __restrict__ Plm,
                                         const int* __restrict__ b2bm,
                                         const int* __restrict__ meta, int mmod,
                                         _Float16* __restrict__ bnh, _Float16* __restrict__ bnl,
                                         int j) {
  const int t = threadIdx.x;
  const int Nb = meta[2 * mmod];
  const size_t o = (size_t)j * DDIM + t * 4;
  if (j >= Nb) {
    *(f16x4*)&bnh[o] = (f16x4)0;
    *(f16x4*)&bnl[o] = (f16x4)0;
    return;
  }
  const int b = b2bm[j];
  f16x4 h = *(const f16x4*)&Phm[(size_t)b * DDIM + t * 4];
  f16x4 l = *(const f16x4*)&Plm[(size_t)b * DDIM + t * 4];
  float v[4]; float s = 0.f;
#pragma unroll
  for (int i = 0; i < 4; ++i) {
    v[i] = (float)h[i] + (float)l[i] * LO_INV;
    s += v[i] * v[i];
  }
  for (int ofs = 32; ofs > 0; ofs >>= 1) s += __shfl_down(s, ofs, 64);
  __shared__ float ls[4];
  if ((t & 63) == 0) ls[t >> 6] = s;
  __syncthreads();
  const float inv = 1.0f / fmaxf(sqrtf(ls[0] + ls[1] + ls[2] + ls[3]), 1e-8f);
  f16x4 hv, lv;
#pragma unroll
  for (int i = 0; i < 4; ++i) {
    float x = v[i] * inv;
    hv[i] = (_Float16)x;
    lv[i] = (_Float16)((x - (float)hv[i]) * LO_SCALE);
  }
  *(f16x4*)&bnh[o] = hv;
  *(f16x4*)&bnl[o] = lv;
}

// ---- combo: knn_fill[m] (4096 blocks) + build_bnk[m2] (8192 blocks) --------
__global__ void knn_bnk_kernel(const float* __restrict__ cvals, const int* __restrict__ cidx,
                               _Float16* __restrict__ Phm, _Float16* __restrict__ Plm,
                               const int* __restrict__ b2bm, const int* __restrict__ qrw_m,
                               const int* __restrict__ meta, int mmod,
                               const _Float16* __restrict__ Phm2, const _Float16* __restrict__ Plm2,
                               const int* __restrict__ b2bm2, int mmod2,
                               _Float16* __restrict__ bnh, _Float16* __restrict__ bnl) {
  const int b = blockIdx.x;
  if (b < 4096) knn_body(cvals, cidx, Phm, Plm, b2bm, qrw_m, meta, mmod, b);
  else          bnk_body(Phm2, Plm2, b2bm2, meta, mmod2, bnh, bnl, b - 4096);
}

__device__ __forceinline__ void zt_body(const int* __restrict__ miss,
                                        const int* __restrict__ meta,
                                        _Float16* __restrict__ P, int row, int m) {
  if (miss[row] != m + 1) return;
  if (row < meta[2 * m]) return;
  f16x4 z = (f16x4)0;
  const size_t o = (size_t)row * DDIM + threadIdx.x * 4;
  *(f16x4*)&P[(size_t)(2 * m) * PSZ + o] = z;
  *(f16x4*)&P[(size_t)(2 * m + 1) * PSZ + o] = z;
}

// ---- combo: knn_fill[2] (4096) + zero_tail (24576) + tsplit W1 (3072) ------
__global__ void final_combo(const float* __restrict__ cvals, const int* __restrict__ cidx,
                            _Float16* __restrict__ Phm, _Float16* __restrict__ Plm,
                            const int* __restrict__ b2bm, const int* __restrict__ qrw_m,
                            const int* __restrict__ meta, int mmod,
                            const int* __restrict__ miss, _Float16* __restrict__ P,
                            const float* __restrict__ W1, _Float16* __restrict__ W1t) {
  const int b = blockIdx.x;
  if (b < 4096) {
    knn_body(cvals, cidx, Phm, Plm, b2bm, qrw_m, meta, mmod, b);
  } else if (b < 4096 + 24576) {
    const int j = b - 4096;
    zt_body(miss, meta, P, j & 8191, j >> 13);
  } else {
    const int j = b - 4096 - 24576;
    tsplit_body(W1, W1t, (_Float16*)nullptr, 3072, 1024, j % 96, j / 96, threadIdx.x);
  }
}

// ---- MFMA fp16 GEMM: H = relu(concat(P hi-planes) @ W1 + b1), fp16 out -----
__launch_bounds__(256, 2)
__global__ void gemm_h1_mfma(const _Float16* __restrict__ P, const _Float16* __restrict__ W1t,
                             const float* __restrict__ bias, _Float16* __restrict__ H) {
  const int K = 3072;
  __shared__ __align__(16) _Float16 Abuf[128 * 64];
  __shared__ __align__(16) _Float16 Bbuf[128 * 64];
  const int t = threadIdx.x;
  const int w = t >> 6, ln = t & 63;
  const int n0 = blockIdx.x * 128, m0 = blockIdx.y * 128;
  const int moff = (w & 1) * 64, noff = (w >> 1) * 64;
  const int lq = ln >> 4, lr = ln & 15;

  size_t aoff[4]; const _Float16* bs[4];
  _Float16* ad[4]; _Float16* bd[4];
#pragma unroll
  for (int p = 0; p < 4; ++p) {
    int r = p * 32 + w * 8 + (ln >> 3);
    int l = (ln & 7) ^ (r & 7);
    aoff[p] = ((size_t)(m0 + r) << 10) + (size_t)(l * 8);
    bs[p] = W1t + (size_t)(n0 + r) * K + l * 8;
    ad[p] = &Abuf[(p * 32 + w * 8) * 64];
    bd[p] = &Bbuf[(p * 32 + w * 8) * 64];
  }

  f32x4 acc[4][4] = {};

  for (int k0 = 0; k0 < K; k0 += 64) {
    const _Float16* aplane = P + ((size_t)(k0 >> 10) * 2) * PSZ + (k0 & 1023);
#pragma unroll
    for (int p = 0; p < 4; ++p) {
      gload_lds16(aplane + aoff[p], ad[p]);
      gload_lds16(bs[p] + k0, bd[p]);
    }
    __syncthreads();
#pragma unroll
    for (int ks = 0; ks < 2; ++ks) {
      f16x8 a[4];
#pragma unroll
      for (int mt = 0; mt < 4; ++mt) {
        int r = moff + mt * 16 + lr;
        a[mt] = *(f16x8*)&Abuf[r * 64 + ((ks * 4 + lq) ^ (r & 7)) * 8];
      }
#pragma unroll
      for (int nt = 0; nt < 4; ++nt) {
        int r = noff + nt * 16 + lr;
        f16x8 b = *(f16x8*)&Bbuf[r * 64 + ((ks * 4 + lq) ^ (r & 7)) * 8];
#pragma unroll
        for (int mt = 0; mt < 4; ++mt)
          acc[mt][nt] = __builtin_amdgcn_mfma_f32_16x16x32_f16(a[mt], b, acc[mt][nt], 0, 0, 0);
      }
    }
    __syncthreads();
  }
#pragma unroll
  for (int nt = 0; nt < 4; ++nt) {
    int col = n0 + noff + nt * 16 + lr;
    float bv = bias[col];
#pragma unroll
    for (int mt = 0; mt < 4; ++mt) {
      int row = m0 + moff + mt * 16 + lq * 4;
#pragma unroll
      for (int r = 0; r < 4; ++r)
        H[(size_t)(row + r) * DDIM + col] = (_Float16)fmaxf(acc[mt][nt][r] + bv, 0.f);
    }
  }
}

__global__ void out_kernel(const _Float16* __restrict__ h1, const float* __restrict__ w2,
                           const float* __restrict__ b2p, float* __restrict__ out) {
  const int row = blockIdx.x, t = threadIdx.x;
  f16x4 h = *(const f16x4*)&h1[(size_t)row * DDIM + t * 4];
  float4 w = *(const float4*)&w2[t * 4];
  float s = (float)h[0] * w.x + (float)h[1] * w.y + (float)h[2] * w.z + (float)h[3] * w.w;
  for (int o = 32; o > 0; o >>= 1) s += __shfl_down(s, o, 64);
  __shared__ float ls[4];
  if ((t & 63) == 0) ls[t >> 6] = s;
  __syncthreads();
  if (t == 0) out[row] = ls[0] + ls[1] + ls[2] + ls[3] + b2p[0];
}

__global__ void build_bnk(const _Float16* __restrict__ Phm, const _Float16* __restrict__ Plm,
                          const int* __restrict__ b2bm, const int* __restrict__ meta,
                          int mmod, _Float16* __restrict__ bnh, _Float16* __restrict__ bnl) {
  bnk_body(Phm, Plm, b2bm, meta, mmod, bnh, bnl, blockIdx.x);
}

extern "C" void kernel_launch(void* const* d_in, const int* in_sizes, int n_in,
                              void* d_out, int out_size, void* d_ws, size_t ws_size,
                              hipStream_t stream) {
  const float* xs[3] = {(const float*)d_in[0], (const float*)d_in[1], (const float*)d_in[2]};
  const int* miss = (const int*)d_in[3];
  const float* Wm[3] = {(const float*)d_in[4], (const float*)d_in[6], (const float*)d_in[8]};
  const float* bm[3] = {(const float*)d_in[5], (const float*)d_in[7], (const float*)d_in[9]};
  const float* W1 = (const float*)d_in[10];
  const float* b1 = (const float*)d_in[11];
  const float* W2 = (const float*)d_in[12];
  const float* b2v = (const float*)d_in[13];

  char* base = (char*)d_ws;
  size_t off = 0;
  auto carve = [&](size_t bytes) -> void* {
    void* p = base + off;
    off += (bytes + 255) & ~(size_t)255;
    return p;
  };
  int*   meta  = (int*)carve(256);
  int*   b2b   = (int*)carve((size_t)3 * NB_ROWS * sizeof(int));
  int*   qrw   = (int*)carve((size_t)3 * 4096 * sizeof(int));
  _Float16* P = (_Float16*)carve((size_t)6 * PSZ * sizeof(_Float16));  // 96 MB
  char* R1 = (char*)carve((size_t)72 * 1024 * 1024);
  if (off > ws_size) return;  // ~168.1 MB

  const size_t MB = 1024 * 1024;
  // phase 1 aliases:
  _Float16* A2h = (_Float16*)R1;                 // 32 MB
  _Float16* A2l = (_Float16*)(R1 + 32 * MB);     // 32 MB
  _Float16* wth = (_Float16*)(R1 + 64 * MB);     // 4 MB
  _Float16* wtl = (_Float16*)(R1 + 68 * MB);     // 4 MB
  // phase 2 aliases:
  _Float16* bnkh = (_Float16*)R1;                // 16 MB
  _Float16* bnkl = (_Float16*)(R1 + 16 * MB);    // 16 MB
  _Float16* Qh   = (_Float16*)(R1 + 32 * MB);    // 8 MB (4096 x 1024 f16)
  _Float16* Ql   = (_Float16*)(R1 + 40 * MB);    // 8 MB
  float*    cvals = (float*)(R1 + 48 * MB);      // 3 MB (4096 x 64 x 3)
  int*      cidx  = (int*)(R1 + 52 * MB);        // 3 MB
  // phase 3 aliases:
  _Float16* W1t   = (_Float16*)R1;               // 6 MB (overlaps dead bank[2])
  _Float16* h1f16 = (_Float16*)(R1 + 32 * MB);   // 16 MB

  scan_kernel<<<dim3(3), dim3(256), 0, stream>>>(miss, meta, b2b, qrw);

  for (int m = 0; m < 3; ++m) {
    prep_kernel<<<dim3(10240), dim3(256), 0, stream>>>(Wm[m], wth, wtl, xs[m], A2h, A2l);
    gemm_proj_mfma<<<dim3(8, 64), dim3(256), 0, stream>>>(
        A2h, A2l, wth, wtl, bm[m], P + (size_t)(2 * m) * PSZ, P + (size_t)(2 * m + 1) * PSZ);
  }

  build_bnk<<<dim3(NB_ROWS), dim3(256), 0, stream>>>(
      P, P + PSZ, b2b, meta, 0, bnkh, bnkl);
  for (int m = 0; m < 3; ++m) {
    qgather<<<dim3(4096), dim3(256), 0, stream>>>(
        bnkh, bnkl, qrw + m * 4096, meta, m, Qh, Ql);
    gemm_sim_topk<<<dim3(64, 32), dim3(256), 0, stream>>>(
        bnkh, bnkl, Qh, Ql, meta, miss, m, cvals, cidx);
    if (m < 2) {
      // knn_fill[m] + build_bnk[m+1] in one launch (independent block ranges)
      knn_bnk_kernel<<<dim3(4096 + NB_ROWS), dim3(256), 0, stream>>>(
          cvals, cidx, P + (size_t)(2 * m) * PSZ, P + (size_t)(2 * m + 1) * PSZ,
          b2b + m * NB_ROWS, qrw + m * 4096, meta, m,
          P + (size_t)(2 * (m + 1)) * PSZ, P + (size_t)(2 * (m + 1) + 1) * PSZ,
          b2b + (m + 1) * NB_ROWS, m + 1, bnkh, bnkl);
    } else {
      // knn_fill[2] + zero_tail + tsplit(W1) in one launch
      final_combo<<<dim3(4096 + 3 * NB_ROWS + 3072), dim3(256), 0, stream>>>(
          cvals, cidx, P + (size_t)(2 * m) * PSZ, P + (size_t)(2 * m + 1) * PSZ,
          b2b + m * NB_ROWS, qrw + m * 4096, meta, m, miss, P, W1, W1t);
    }
  }

  gemm_h1_mfma<<<dim3(8, 64), dim3(256), 0, stream>>>(P, W1t, b1, h1f16);
  out_kernel<<<dim3(NB_ROWS), dim3(256), 0, stream>>>(h1f16, W2, b2v, (float*)d_out);
}